// Round 1
// baseline (296.363 us; speedup 1.0000x reference)
//
#include <hip/hip_runtime.h>
#include <hip/hip_bf16.h>

// Problem constants
#define B 8
#define H 3584
#define NH 28
#define KVH 4
#define HD 128
#define GS 7
#define MB 16
#define BS 256
#define R 32           // B*KVH
#define SCALE 0.08838834764831845f

__device__ __forceinline__ float dot4(float4 a, float4 b) {
    return fmaf(a.x, b.x, fmaf(a.y, b.y, fmaf(a.z, b.z, a.w * b.w)));
}

// Sum across a 16-lane DPP row; every lane in the row ends with the row sum.
// Direction-agnostic ladder (quad xor1, quad xor2, half-mirror, mirror).
__device__ __forceinline__ float red16(float v) {
    v += __int_as_float(__builtin_amdgcn_update_dpp(0, __float_as_int(v), 0xB1,  0xf, 0xf, false)); // quad_perm [1,0,3,2]
    v += __int_as_float(__builtin_amdgcn_update_dpp(0, __float_as_int(v), 0x4E,  0xf, 0xf, false)); // quad_perm [2,3,0,1]
    v += __int_as_float(__builtin_amdgcn_update_dpp(0, __float_as_int(v), 0x141, 0xf, 0xf, false)); // row_half_mirror
    v += __int_as_float(__builtin_amdgcn_update_dpp(0, __float_as_int(v), 0x140, 0xf, 0xf, false)); // row_mirror
    return v;
}

// ---------------- Kernel 1: fused QKV GEMV ----------------
// grid = 1152 blocks of 64 (1 wave). Wave handles 4 consecutive output features
// across all 8 batch rows. Features 0..3583 -> q, 3584..4095 -> k, 4096..4607 -> v.
__global__ __launch_bounds__(64) void qkv_kernel(
    const float* __restrict__ hid,
    const float* __restrict__ qw, const float* __restrict__ qb,
    const float* __restrict__ kw, const float* __restrict__ kb,
    const float* __restrict__ vw, const float* __restrict__ vb,
    float* __restrict__ qout, float* __restrict__ kout, float* __restrict__ vout)
{
    const int wave = blockIdx.x;
    const int lane = threadIdx.x;
    const int f0 = wave * 4;

    const float* W; const float* Bv; float* Out; int fbase; int ostr;
    if (wave < 896)       { W = qw; Bv = qb; Out = qout; fbase = f0;        ostr = 3584; }
    else if (wave < 1024) { W = kw; Bv = kb; Out = kout; fbase = f0 - 3584; ostr = 512;  }
    else                  { W = vw; Bv = vb; Out = vout; fbase = f0 - 4096; ostr = 512;  }

    const float4* wr0 = (const float4*)(W + (size_t)(fbase + 0) * H);
    const float4* wr1 = (const float4*)(W + (size_t)(fbase + 1) * H);
    const float4* wr2 = (const float4*)(W + (size_t)(fbase + 2) * H);
    const float4* wr3 = (const float4*)(W + (size_t)(fbase + 3) * H);
    const float4* h4 = (const float4*)hid;

    float acc[4][8];
    #pragma unroll
    for (int i = 0; i < 4; ++i)
        #pragma unroll
        for (int b = 0; b < 8; ++b) acc[i][b] = 0.f;

    for (int it = 0; it < 14; ++it) {
        const int c = it * 64 + lane;          // float4 column, < 896
        float4 w0 = wr0[c], w1 = wr1[c], w2 = wr2[c], w3 = wr3[c];
        float4 hb[8];
        #pragma unroll
        for (int b = 0; b < 8; ++b) hb[b] = h4[b * 896 + c];
        #pragma unroll
        for (int b = 0; b < 8; ++b) {
            acc[0][b] += dot4(w0, hb[b]);
            acc[1][b] += dot4(w1, hb[b]);
            acc[2][b] += dot4(w2, hb[b]);
            acc[3][b] += dot4(w3, hb[b]);
        }
    }
    // full-wave butterfly reduction of all 32 accumulators
    #pragma unroll
    for (int i = 0; i < 4; ++i)
        #pragma unroll
        for (int b = 0; b < 8; ++b)
            #pragma unroll
            for (int m = 1; m < 64; m <<= 1)
                acc[i][b] += __shfl_xor(acc[i][b], m);

    if (lane == 0) {
        #pragma unroll
        for (int i = 0; i < 4; ++i) {
            const float bias = Bv[fbase + i];
            #pragma unroll
            for (int b = 0; b < 8; ++b)
                Out[b * ostr + fbase + i] = acc[i][b] + bias;
        }
    }
}

// ---------------- Kernel 2: RoPE (q in-place, k) + KV-cache scatter ----------------
// grid = B blocks of 256.
__global__ __launch_bounds__(256) void rope_cache_kernel(
    float* __restrict__ q, const float* __restrict__ kraw, const float* __restrict__ vraw,
    const float* __restrict__ cosb, const float* __restrict__ sinb,
    const int* __restrict__ btab, const int* __restrict__ cs,
    float* __restrict__ kpool, float* __restrict__ vpool)
{
    const int b = blockIdx.x;
    const int tid = threadIdx.x;

    // q rope: 28 heads x 64 pairs = 1792 pairs
    for (int i = tid; i < NH * 64; i += 256) {
        const int h = i >> 6, dp = i & 63;
        float* base = q + (size_t)b * H + h * HD;
        const float x1 = base[dp], x2 = base[dp + 64];
        const float c1 = cosb[b * HD + dp],      s1 = sinb[b * HD + dp];
        const float c2 = cosb[b * HD + dp + 64], s2 = sinb[b * HD + dp + 64];
        base[dp]      = x1 * c1 - x2 * s1;
        base[dp + 64] = x2 * c2 + x1 * s2;
    }
    // k rope + cache write: 4 heads x 64 pairs = 256 pairs (tid covers exactly)
    {
        const int kvh = tid >> 6, dp = tid & 63;
        const int r = b * KVH + kvh;
        const float* kb_ = kraw + (size_t)r * HD;
        const float x1 = kb_[dp], x2 = kb_[dp + 64];
        const float c1 = cosb[b * HD + dp],      s1 = sinb[b * HD + dp];
        const float c2 = cosb[b * HD + dp + 64], s2 = sinb[b * HD + dp + 64];
        const int pos = cs[r] - 1;
        const int blk = btab[r * MB + (pos >> 8)];
        const int off = pos & 255;
        float* dst = kpool + ((size_t)blk * BS + off) * HD;
        dst[dp]      = x1 * c1 - x2 * s1;
        dst[dp + 64] = x2 * c2 + x1 * s2;
    }
    // v cache write: 4 heads x 128 dims = 512 values
    for (int i = tid; i < KVH * HD; i += 256) {
        const int r = b * KVH + (i >> 7);
        const int d = i & 127;
        const int pos = cs[r] - 1;
        const int blk = btab[r * MB + (pos >> 8)];
        const int off = pos & 255;
        vpool[((size_t)blk * BS + off) * HD + d] = vraw[(size_t)b * KVH * HD + i];
    }
}

// ---------------- Kernel 3: flash-decode partials ----------------
// grid = (MB pages, R rows), 256 threads. Produces per-(r,page,g): m, l, o[128].
__global__ __launch_bounds__(256) void attn_partial_kernel(
    const float* __restrict__ q, const float* __restrict__ kpool, const float* __restrict__ vpool,
    const int* __restrict__ btab, const int* __restrict__ cs,
    float* __restrict__ pm, float* __restrict__ pl, float* __restrict__ po)
{
    const int page = blockIdx.x;
    const int r = blockIdx.y;
    const int seqlen = cs[r];
    const int page_start = page << 8;
    if (page_start >= seqlen) return;
    const int valid_n = min(BS, seqlen - page_start);
    const int blk = btab[r * MB + page];
    const float* Kp = kpool + (size_t)blk * BS * HD;
    const float* Vp = vpool + (size_t)blk * BS * HD;

    const int tid = threadIdx.x;
    const int w = tid >> 6;        // wave 0..3 (token quarter)
    const int lane = tid & 63;
    const int tl = lane >> 4;      // token within group of 4
    const int dg = lane & 15;      // dim-group: dims [dg*8, dg*8+8)

    __shared__ float s_lds[GS][BS];      // scores, then p
    __shared__ float o_red[4][GS][HD];   // per-quarter partial PV
    __shared__ float red[GS][4];
    __shared__ float m_sh[GS];

    // q fragments: 7 heads x 8 dims per lane
    float4 qa[GS], qb2[GS];
    #pragma unroll
    for (int g = 0; g < GS; ++g) {
        const float4* qp = (const float4*)(q + (size_t)(r * GS + g) * HD + dg * 8);
        qa[g] = qp[0]; qb2[g] = qp[1];
    }

    // ---- Phase A: scores ----
    const int tq_wave = min(64, max(0, valid_n - w * 64));
    for (int i = 0; i < 16; ++i) {
        const int tg = i * 4;
        if (tg >= tq_wave) break;                  // wave-uniform
        const int t = w * 64 + tg + tl;            // < 256 always, safe to load
        const float4* kp4 = (const float4*)(Kp + (size_t)t * HD + dg * 8);
        const float4 ka = kp4[0], kb = kp4[1];
        #pragma unroll
        for (int g = 0; g < GS; ++g) {
            float v = dot4(qa[g], ka) + dot4(qb2[g], kb);
            v = red16(v);                          // DPP row reduce (VALU pipe)
            if (dg == 0) s_lds[g][t] = v * SCALE;
        }
    }
    __syncthreads();

    // ---- Phase B: softmax partial (m, l, p) ----
    {
        const int t = tid;
        const bool valid = t < valid_n;
        #pragma unroll
        for (int g = 0; g < GS; ++g) {
            float sv = valid ? s_lds[g][t] : -3.0e38f;
            #pragma unroll
            for (int m = 1; m < 64; m <<= 1) sv = fmaxf(sv, __shfl_xor(sv, m));
            if (lane == 0) red[g][w] = sv;
        }
        __syncthreads();
        if (tid < GS)
            m_sh[tid] = fmaxf(fmaxf(red[tid][0], red[tid][1]), fmaxf(red[tid][2], red[tid][3]));
        __syncthreads();
        #pragma unroll
        for (int g = 0; g < GS; ++g) {
            float p = valid ? __expf(s_lds[g][t] - m_sh[g]) : 0.f;
            s_lds[g][t] = p;
            #pragma unroll
            for (int m = 1; m < 64; m <<= 1) p += __shfl_xor(p, m);
            if (lane == 0) red[g][w] = p;
        }
        __syncthreads();
        if (tid < GS) {
            const int idx = (r * MB + page) * GS + tid;
            pm[idx] = m_sh[tid];
            pl[idx] = red[tid][0] + red[tid][1] + red[tid][2] + red[tid][3];
        }
    }

    // ---- Phase C: PV partial. Wave = token quarter; lane owns dims {2*lane, 2*lane+1}. ----
    float acc[GS][2];
    #pragma unroll
    for (int g = 0; g < GS; ++g) { acc[g][0] = 0.f; acc[g][1] = 0.f; }
    {
        const int t0 = w * 64;
        const int tq = min(64, max(0, valid_n - t0));
        const int tq4 = (tq + 3) & ~3;
        for (int t = 0; t < tq4; t += 4) {
            float4 p4[GS];
            #pragma unroll
            for (int g = 0; g < GS; ++g) p4[g] = *(const float4*)&s_lds[g][t0 + t];  // broadcast
            #pragma unroll
            for (int k = 0; k < 4; ++k) {
                const float2 v2 = *(const float2*)(Vp + (size_t)(t0 + t + k) * HD + lane * 2);
                #pragma unroll
                for (int g = 0; g < GS; ++g) {
                    const float pk = (k == 0) ? p4[g].x : (k == 1) ? p4[g].y : (k == 2) ? p4[g].z : p4[g].w;
                    acc[g][0] = fmaf(pk, v2.x, acc[g][0]);
                    acc[g][1] = fmaf(pk, v2.y, acc[g][1]);
                }
            }
        }
    }
    #pragma unroll
    for (int g = 0; g < GS; ++g) {
        o_red[w][g][lane * 2]     = acc[g][0];
        o_red[w][g][lane * 2 + 1] = acc[g][1];
    }
    __syncthreads();
    for (int idx = tid; idx < GS * HD; idx += 256) {
        const int g = idx >> 7, d = idx & 127;
        const float v = o_red[0][g][d] + o_red[1][g][d] + o_red[2][g][d] + o_red[3][g][d];
        po[((size_t)(r * MB + page) * GS + g) * HD + d] = v;
    }
}

// ---------------- Kernel 4: combine page partials ----------------
// grid = R*GS blocks of 128 (thread = dim).
__global__ __launch_bounds__(128) void combine_kernel(
    const float* __restrict__ pm, const float* __restrict__ pl, const float* __restrict__ po,
    const int* __restrict__ cs, float* __restrict__ att)
{
    const int bx = blockIdx.x;
    const int r = bx / GS, g = bx % GS;
    const int npages = (cs[r] + BS - 1) >> 8;
    float M = -3.0e38f;
    for (int p = 0; p < npages; ++p) M = fmaxf(M, pm[(r * MB + p) * GS + g]);
    float L = 0.f, acc = 0.f;
    const int d = threadIdx.x;
    for (int p = 0; p < npages; ++p) {
        const int idx = (r * MB + p) * GS + g;
        const float wgt = __expf(pm[idx] - M);
        L   += wgt * pl[idx];
        acc += wgt * po[(size_t)idx * HD + d];
    }
    att[(size_t)(r * GS + g) * HD + d] = acc / L;
}

// ---------------- Kernel 5: O projection GEMV ----------------
// grid = 896 blocks of 64 (1 wave, 4 features x 8 batches).
__global__ __launch_bounds__(64) void oproj_kernel(
    const float* __restrict__ att, const float* __restrict__ ow, float* __restrict__ out)
{
    const int wave = blockIdx.x;
    const int lane = threadIdx.x;
    const int f0 = wave * 4;

    const float4* wr0 = (const float4*)(ow + (size_t)(f0 + 0) * H);
    const float4* wr1 = (const float4*)(ow + (size_t)(f0 + 1) * H);
    const float4* wr2 = (const float4*)(ow + (size_t)(f0 + 2) * H);
    const float4* wr3 = (const float4*)(ow + (size_t)(f0 + 3) * H);
    const float4* a4 = (const float4*)att;

    float acc[4][8];
    #pragma unroll
    for (int i = 0; i < 4; ++i)
        #pragma unroll
        for (int b = 0; b < 8; ++b) acc[i][b] = 0.f;

    for (int it = 0; it < 14; ++it) {
        const int c = it * 64 + lane;
        float4 w0 = wr0[c], w1 = wr1[c], w2 = wr2[c], w3 = wr3[c];
        float4 hb[8];
        #pragma unroll
        for (int b = 0; b < 8; ++b) hb[b] = a4[b * 896 + c];
        #pragma unroll
        for (int b = 0; b < 8; ++b) {
            acc[0][b] += dot4(w0, hb[b]);
            acc[1][b] += dot4(w1, hb[b]);
            acc[2][b] += dot4(w2, hb[b]);
            acc[3][b] += dot4(w3, hb[b]);
        }
    }
    #pragma unroll
    for (int i = 0; i < 4; ++i)
        #pragma unroll
        for (int b = 0; b < 8; ++b)
            #pragma unroll
            for (int m = 1; m < 64; m <<= 1)
                acc[i][b] += __shfl_xor(acc[i][b], m);

    if (lane == 0) {
        #pragma unroll
        for (int i = 0; i < 4; ++i)
            #pragma unroll
            for (int b = 0; b < 8; ++b)
                out[b * H + f0 + i] = acc[i][b];
    }
}

extern "C" void kernel_launch(void* const* d_in, const int* in_sizes, int n_in,
                              void* d_out, int out_size, void* d_ws, size_t ws_size,
                              hipStream_t stream) {
    (void)in_sizes; (void)n_in; (void)out_size; (void)ws_size;
    const float* hid  = (const float*)d_in[0];
    const float* cosb = (const float*)d_in[1];
    const float* sinb = (const float*)d_in[2];
    const float* qw   = (const float*)d_in[3];
    const float* qb   = (const float*)d_in[4];
    const float* kw   = (const float*)d_in[5];
    const float* kb   = (const float*)d_in[6];
    const float* vw   = (const float*)d_in[7];
    const float* vb   = (const float*)d_in[8];
    const float* ow   = (const float*)d_in[9];
    float* kpool      = (float*)d_in[10];
    float* vpool      = (float*)d_in[11];
    const int* btab   = (const int*)d_in[12];
    const int* cs     = (const int*)d_in[13];

    float* ws   = (float*)d_ws;
    float* q    = ws;             // 28672 (raw q feats, then roped in-place)
    float* kraw = q + 28672;      // 4096
    float* vraw = kraw + 4096;    // 4096
    float* att  = vraw + 4096;    // 28672
    float* pm   = att + 28672;    // 3584
    float* pl   = pm + 3584;      // 3584
    float* po   = pl + 3584;      // 458752

    hipLaunchKernelGGL(qkv_kernel, dim3(1152), dim3(64), 0, stream,
                       hid, qw, qb, kw, kb, vw, vb, q, kraw, vraw);
    hipLaunchKernelGGL(rope_cache_kernel, dim3(B), dim3(256), 0, stream,
                       q, kraw, vraw, cosb, sinb, btab, cs, kpool, vpool);
    hipLaunchKernelGGL(attn_partial_kernel, dim3(MB, R), dim3(256), 0, stream,
                       q, kpool, vpool, btab, cs, pm, pl, po);
    hipLaunchKernelGGL(combine_kernel, dim3(R * GS), dim3(128), 0, stream,
                       pm, pl, po, cs, att);
    hipLaunchKernelGGL(oproj_kernel, dim3(896), dim3(64), 0, stream,
                       att, ow, (float*)d_out);
}

// Round 2
// 289.781 us; speedup vs baseline: 1.0227x; 1.0227x over previous
//
#include <hip/hip_runtime.h>
#include <hip/hip_bf16.h>

// Problem constants
#define B 8
#define H 3584
#define NH 28
#define KVH 4
#define HD 128
#define GS 7
#define MB 16
#define BS 256
#define R 32           // B*KVH
#define NCHUNK 64      // MB*BS/64 chunks of 64 tokens per row
#define SCALE 0.08838834764831845f

__device__ __forceinline__ float dot4(float4 a, float4 b) {
    return fmaf(a.x, b.x, fmaf(a.y, b.y, fmaf(a.z, b.z, a.w * b.w)));
}

// Sum across a 16-lane DPP row; every lane in the row ends with the row sum.
__device__ __forceinline__ float red16(float v) {
    v += __int_as_float(__builtin_amdgcn_update_dpp(0, __float_as_int(v), 0xB1,  0xf, 0xf, false)); // quad_perm [1,0,3,2]
    v += __int_as_float(__builtin_amdgcn_update_dpp(0, __float_as_int(v), 0x4E,  0xf, 0xf, false)); // quad_perm [2,3,0,1]
    v += __int_as_float(__builtin_amdgcn_update_dpp(0, __float_as_int(v), 0x141, 0xf, 0xf, false)); // row_half_mirror
    v += __int_as_float(__builtin_amdgcn_update_dpp(0, __float_as_int(v), 0x140, 0xf, 0xf, false)); // row_mirror
    return v;
}

// ---------------- Kernel 1: fused QKV GEMV ----------------
// grid = 1152 blocks x 256 threads (4 waves). Block handles 4 consecutive output
// features across all 8 batch rows; the 4 waves split the H dimension, then
// LDS tree-combine. Features 0..3583 -> q, 3584..4095 -> k, 4096..4607 -> v.
__global__ __launch_bounds__(256) void qkv_kernel(
    const float* __restrict__ hid,
    const float* __restrict__ qw, const float* __restrict__ qb,
    const float* __restrict__ kw, const float* __restrict__ kb,
    const float* __restrict__ vw, const float* __restrict__ vb,
    float* __restrict__ qout, float* __restrict__ kout, float* __restrict__ vout)
{
    const int blk = blockIdx.x;
    const int tid = threadIdx.x;
    const int w = tid >> 6;
    const int f0 = blk * 4;

    const float* W; const float* Bv; float* Out; int fbase; int ostr;
    if (blk < 896)       { W = qw; Bv = qb; Out = qout; fbase = f0;        ostr = 3584; }
    else if (blk < 1024) { W = kw; Bv = kb; Out = kout; fbase = f0 - 3584; ostr = 512;  }
    else                 { W = vw; Bv = vb; Out = vout; fbase = f0 - 4096; ostr = 512;  }

    const float4* wr0 = (const float4*)(W + (size_t)(fbase + 0) * H);
    const float4* wr1 = (const float4*)(W + (size_t)(fbase + 1) * H);
    const float4* wr2 = (const float4*)(W + (size_t)(fbase + 2) * H);
    const float4* wr3 = (const float4*)(W + (size_t)(fbase + 3) * H);
    const float4* h4 = (const float4*)hid;

    float acc[4][8];
    #pragma unroll
    for (int i = 0; i < 4; ++i)
        #pragma unroll
        for (int b = 0; b < 8; ++b) acc[i][b] = 0.f;

    // 896 float4 columns split over 256 threads: k=0..2 full, k=3 only tid<128
    #pragma unroll
    for (int k = 0; k < 4; ++k) {
        const int c = tid + k * 256;
        if (c < 896) {
            float4 w0 = wr0[c], w1 = wr1[c], w2 = wr2[c], w3 = wr3[c];
            float4 hb[8];
            #pragma unroll
            for (int b = 0; b < 8; ++b) hb[b] = h4[b * 896 + c];
            #pragma unroll
            for (int b = 0; b < 8; ++b) {
                acc[0][b] += dot4(w0, hb[b]);
                acc[1][b] += dot4(w1, hb[b]);
                acc[2][b] += dot4(w2, hb[b]);
                acc[3][b] += dot4(w3, hb[b]);
            }
        }
    }
    // wave butterfly
    #pragma unroll
    for (int i = 0; i < 4; ++i)
        #pragma unroll
        for (int b = 0; b < 8; ++b)
            #pragma unroll
            for (int m = 1; m < 64; m <<= 1)
                acc[i][b] += __shfl_xor(acc[i][b], m);

    __shared__ float part[4][32];
    if ((tid & 63) == 0) {
        #pragma unroll
        for (int i = 0; i < 4; ++i)
            #pragma unroll
            for (int b = 0; b < 8; ++b)
                part[w][i * 8 + b] = acc[i][b];
    }
    __syncthreads();
    if (tid < 32) {
        const int i = tid >> 3, b = tid & 7;
        const float v = part[0][tid] + part[1][tid] + part[2][tid] + part[3][tid];
        Out[b * ostr + fbase + i] = v + Bv[fbase + i];
    }
}

// ---------------- Kernel 2: RoPE (q in-place, k) + KV-cache scatter ----------------
// grid = 32 blocks of 256. Block = (batch b, quarter qtr): 7 q-heads + 1 kv-head.
__global__ __launch_bounds__(256) void rope_cache_kernel(
    float* __restrict__ q, const float* __restrict__ kraw, const float* __restrict__ vraw,
    const float* __restrict__ cosb, const float* __restrict__ sinb,
    const int* __restrict__ btab, const int* __restrict__ cs,
    float* __restrict__ kpool, float* __restrict__ vpool)
{
    const int b = blockIdx.x >> 2;
    const int qtr = blockIdx.x & 3;
    const int tid = threadIdx.x;

    // q rope: heads qtr*7 .. qtr*7+6 -> 448 pairs
    for (int i = tid; i < 448; i += 256) {
        const int h = qtr * 7 + (i >> 6), dp = i & 63;
        float* base = q + (size_t)b * H + h * HD;
        const float x1 = base[dp], x2 = base[dp + 64];
        const float c1 = cosb[b * HD + dp],      s1 = sinb[b * HD + dp];
        const float c2 = cosb[b * HD + dp + 64], s2 = sinb[b * HD + dp + 64];
        base[dp]      = x1 * c1 - x2 * s1;
        base[dp + 64] = x2 * c2 + x1 * s2;
    }
    const int r = b * KVH + qtr;
    const int pos = cs[r] - 1;
    const int pb = btab[r * MB + (pos >> 8)];
    const int off = pos & 255;
    // k rope + cache write: 64 pairs
    if (tid < 64) {
        const int dp = tid;
        const float* kb_ = kraw + (size_t)r * HD;
        const float x1 = kb_[dp], x2 = kb_[dp + 64];
        const float c1 = cosb[b * HD + dp],      s1 = sinb[b * HD + dp];
        const float c2 = cosb[b * HD + dp + 64], s2 = sinb[b * HD + dp + 64];
        float* dst = kpool + ((size_t)pb * BS + off) * HD;
        dst[dp]      = x1 * c1 - x2 * s1;
        dst[dp + 64] = x2 * c2 + x1 * s2;
    }
    // v cache write: 128 dims
    if (tid < 128) {
        vpool[((size_t)pb * BS + off) * HD + tid] = vraw[(size_t)r * HD + tid];
    }
}

// ---------------- Kernel 3: flash-decode partials (barrier-free) ----------------
// grid = (MB pages, R rows), 256 threads = 4 independent waves, each owning a
// 64-token chunk. Per-wave LDS only (same-wave RAW -> no __syncthreads).
// Writes per-(r,chunk,g): m, l, o[128].
__global__ __launch_bounds__(256) void attn_partial_kernel(
    const float* __restrict__ q, const float* __restrict__ kpool, const float* __restrict__ vpool,
    const int* __restrict__ btab, const int* __restrict__ cs,
    float* __restrict__ pm, float* __restrict__ pl, float* __restrict__ po)
{
    const int page = blockIdx.x;
    const int r = blockIdx.y;
    const int seqlen = cs[r];
    const int page_start = page << 8;
    if (page_start >= seqlen) return;

    const int tid = threadIdx.x;
    const int w = tid >> 6;            // wave -> 64-token chunk within page
    const int lane = tid & 63;
    const int chunk = page * 4 + w;    // 0..63 global chunk id
    const int c0 = chunk * 64;
    if (c0 >= seqlen) return;          // wave-uniform exit, no barriers in kernel
    const int vt = min(64, seqlen - c0);

    const int blk = btab[r * MB + page];
    const float* Kp = kpool + ((size_t)blk * BS + w * 64) * HD;
    const float* Vp = vpool + ((size_t)blk * BS + w * 64) * HD;

    __shared__ float s_p[4][GS][64];   // 7 KB: per-wave score/p buffer

    const int tl = lane >> 4;          // token within group of 4
    const int dg = lane & 15;          // dim-group: dims [dg*8, dg*8+8)

    // q fragments: 7 heads x 8 dims per lane
    float4 qa[GS], qb2[GS];
    #pragma unroll
    for (int g = 0; g < GS; ++g) {
        const float4* qp = (const float4*)(q + (size_t)(r * GS + g) * HD + dg * 8);
        qa[g] = qp[0]; qb2[g] = qp[1];
    }

    // ---- Phase A: scores (16 lanes per token, DPP reduce) ----
    if (vt == 64) {
        #pragma unroll 4
        for (int i = 0; i < 16; ++i) {
            const int t = i * 4 + tl;
            const float4* kp4 = (const float4*)(Kp + (size_t)t * HD + dg * 8);
            const float4 ka = kp4[0], kb = kp4[1];
            #pragma unroll
            for (int g = 0; g < GS; ++g) {
                float v = dot4(qa[g], ka) + dot4(qb2[g], kb);
                v = red16(v);
                if (dg == 0) s_p[w][g][t] = v * SCALE;
            }
        }
    } else {
        const int nI = (vt + 3) >> 2;
        for (int i = 0; i < nI; ++i) {
            const int t = i * 4 + tl;  // may exceed vt (masked later); stays in page
            const float4* kp4 = (const float4*)(Kp + (size_t)t * HD + dg * 8);
            const float4 ka = kp4[0], kb = kp4[1];
            #pragma unroll
            for (int g = 0; g < GS; ++g) {
                float v = dot4(qa[g], ka) + dot4(qb2[g], kb);
                v = red16(v);
                if (dg == 0) s_p[w][g][t] = v * SCALE;
            }
        }
    }

    // ---- Phase B: per-chunk softmax partial. Lane = token. ----
    float mx[GS], lsum[GS];
    #pragma unroll
    for (int g = 0; g < GS; ++g) {
        float sv = (lane < vt) ? s_p[w][g][lane] : -3.0e38f;
        float m_ = sv;
        #pragma unroll
        for (int m = 1; m < 64; m <<= 1) m_ = fmaxf(m_, __shfl_xor(m_, m));
        float p = (lane < vt) ? __expf(sv - m_) : 0.f;
        s_p[w][g][lane] = p;
        float l_ = p;
        #pragma unroll
        for (int m = 1; m < 64; m <<= 1) l_ += __shfl_xor(l_, m);
        mx[g] = m_; lsum[g] = l_;
    }
    const size_t pidx = (size_t)(r * NCHUNK + chunk) * GS;
    if (lane == 0) {
        #pragma unroll
        for (int g = 0; g < GS; ++g) { pm[pidx + g] = mx[g]; pl[pidx + g] = lsum[g]; }
    }

    // ---- Phase C: PV partial. Lane owns dims {2*lane, 2*lane+1}. ----
    float acc[GS][2];
    #pragma unroll
    for (int g = 0; g < GS; ++g) { acc[g][0] = 0.f; acc[g][1] = 0.f; }
    const int vt4 = (vt + 3) & ~3;
    #pragma unroll 2
    for (int t = 0; t < vt4; t += 4) {
        float4 p4[GS];
        #pragma unroll
        for (int g = 0; g < GS; ++g) p4[g] = *(const float4*)&s_p[w][g][t];
        #pragma unroll
        for (int k = 0; k < 4; ++k) {
            const float2 v2 = *(const float2*)(Vp + (size_t)(t + k) * HD + lane * 2);
            #pragma unroll
            for (int g = 0; g < GS; ++g) {
                const float pk = (k == 0) ? p4[g].x : (k == 1) ? p4[g].y : (k == 2) ? p4[g].z : p4[g].w;
                acc[g][0] = fmaf(pk, v2.x, acc[g][0]);
                acc[g][1] = fmaf(pk, v2.y, acc[g][1]);
            }
        }
    }
    #pragma unroll
    for (int g = 0; g < GS; ++g) {
        *(float2*)(po + (pidx + g) * HD + lane * 2) = make_float2(acc[g][0], acc[g][1]);
    }
}

// ---------------- Kernel 4: combine chunk partials (online softmax) ----------------
// grid = R*GS blocks of 128 (thread = dim).
__global__ __launch_bounds__(128) void combine_kernel(
    const float* __restrict__ pm, const float* __restrict__ pl, const float* __restrict__ po,
    const int* __restrict__ cs, float* __restrict__ att)
{
    const int bx = blockIdx.x;
    const int r = bx / GS, g = bx % GS;
    const int nc = (cs[r] + 63) >> 6;
    const int d = threadIdx.x;
    float M = -3.0e38f, L = 0.f, acc = 0.f;
    for (int c = 0; c < nc; ++c) {
        const size_t idx = (size_t)(r * NCHUNK + c) * GS + g;
        const float m = pm[idx];
        const float nM = fmaxf(M, m);
        const float sc = __expf(M - nM);
        const float wg = __expf(m - nM);
        acc = acc * sc + wg * po[idx * HD + d];
        L   = L   * sc + wg * pl[idx];
        M = nM;
    }
    att[(size_t)(r * GS + g) * HD + d] = acc / L;
}

// ---------------- Kernel 5: O projection GEMV ----------------
// grid = 896 blocks x 256 threads, same structure as qkv (no bias).
__global__ __launch_bounds__(256) void oproj_kernel(
    const float* __restrict__ att, const float* __restrict__ ow, float* __restrict__ out)
{
    const int blk = blockIdx.x;
    const int tid = threadIdx.x;
    const int w = tid >> 6;
    const int f0 = blk * 4;

    const float4* wr0 = (const float4*)(ow + (size_t)(f0 + 0) * H);
    const float4* wr1 = (const float4*)(ow + (size_t)(f0 + 1) * H);
    const float4* wr2 = (const float4*)(ow + (size_t)(f0 + 2) * H);
    const float4* wr3 = (const float4*)(ow + (size_t)(f0 + 3) * H);
    const float4* a4 = (const float4*)att;

    float acc[4][8];
    #pragma unroll
    for (int i = 0; i < 4; ++i)
        #pragma unroll
        for (int b = 0; b < 8; ++b) acc[i][b] = 0.f;

    #pragma unroll
    for (int k = 0; k < 4; ++k) {
        const int c = tid + k * 256;
        if (c < 896) {
            float4 w0 = wr0[c], w1 = wr1[c], w2 = wr2[c], w3 = wr3[c];
            float4 hb[8];
            #pragma unroll
            for (int b = 0; b < 8; ++b) hb[b] = a4[b * 896 + c];
            #pragma unroll
            for (int b = 0; b < 8; ++b) {
                acc[0][b] += dot4(w0, hb[b]);
                acc[1][b] += dot4(w1, hb[b]);
                acc[2][b] += dot4(w2, hb[b]);
                acc[3][b] += dot4(w3, hb[b]);
            }
        }
    }
    #pragma unroll
    for (int i = 0; i < 4; ++i)
        #pragma unroll
        for (int b = 0; b < 8; ++b)
            #pragma unroll
            for (int m = 1; m < 64; m <<= 1)
                acc[i][b] += __shfl_xor(acc[i][b], m);

    __shared__ float part[4][32];
    if ((tid & 63) == 0) {
        #pragma unroll
        for (int i = 0; i < 4; ++i)
            #pragma unroll
            for (int b = 0; b < 8; ++b)
                part[w][i * 8 + b] = acc[i][b];
    }
    __syncthreads();
    if (tid < 32) {
        const int i = tid >> 3, b = tid & 7;
        out[b * H + f0 + i] = part[0][tid] + part[1][tid] + part[2][tid] + part[3][tid];
    }
}

extern "C" void kernel_launch(void* const* d_in, const int* in_sizes, int n_in,
                              void* d_out, int out_size, void* d_ws, size_t ws_size,
                              hipStream_t stream) {
    (void)in_sizes; (void)n_in; (void)out_size; (void)ws_size;
    const float* hid  = (const float*)d_in[0];
    const float* cosb = (const float*)d_in[1];
    const float* sinb = (const float*)d_in[2];
    const float* qw   = (const float*)d_in[3];
    const float* qb   = (const float*)d_in[4];
    const float* kw   = (const float*)d_in[5];
    const float* kb   = (const float*)d_in[6];
    const float* vw   = (const float*)d_in[7];
    const float* vb   = (const float*)d_in[8];
    const float* ow   = (const float*)d_in[9];
    float* kpool      = (float*)d_in[10];
    float* vpool      = (float*)d_in[11];
    const int* btab   = (const int*)d_in[12];
    const int* cs     = (const int*)d_in[13];

    float* ws   = (float*)d_ws;
    float* q    = ws;             // 28672
    float* kraw = q + 28672;      // 4096
    float* vraw = kraw + 4096;    // 4096
    float* att  = vraw + 4096;    // 28672
    float* pm   = att + 28672;    // R*NCHUNK*GS = 14336
    float* pl   = pm + 14336;     // 14336
    float* po   = pl + 14336;     // R*NCHUNK*GS*HD = 1835008 (~7.3 MB)

    hipLaunchKernelGGL(qkv_kernel, dim3(1152), dim3(256), 0, stream,
                       hid, qw, qb, kw, kb, vw, vb, q, kraw, vraw);
    hipLaunchKernelGGL(rope_cache_kernel, dim3(32), dim3(256), 0, stream,
                       q, kraw, vraw, cosb, sinb, btab, cs, kpool, vpool);
    hipLaunchKernelGGL(attn_partial_kernel, dim3(MB, R), dim3(256), 0, stream,
                       q, kpool, vpool, btab, cs, pm, pl, po);
    hipLaunchKernelGGL(combine_kernel, dim3(R * GS), dim3(128), 0, stream,
                       pm, pl, po, cs, att);
    hipLaunchKernelGGL(oproj_kernel, dim3(896), dim3(256), 0, stream,
                       att, ow, (float*)d_out);
}